// Round 2
// baseline (39.713 us; speedup 1.0000x reference)
//
#include <hip/hip_runtime.h>

#define TLEN 1461

__device__ __forceinline__ float fast_tanh(float x) {
    // tanh(x) = 1 - 2/(exp(2x)+1); saturates to +-1 without NaN
    float e = __expf(2.0f * x);
    return fmaf(-2.0f, __builtin_amdgcn_rcpf(e + 1.0f), 1.0f);
}

__device__ __forceinline__ float step_fn(float x) {
    // (tanh(5x)+1)*0.5 == sigmoid(10x) = 1/(1+exp(-10x))
    float e = __expf(-10.0f * x);
    return __builtin_amdgcn_rcpf(1.0f + e);
}

// one 16->16 tanh layer; w row-major [16][16] read UNIFORMLY from global
// (compile-time indices + wave-uniform pointer -> backend emits s_load,
// weights live in SGPRs, v_fma takes the SGPR operand directly)
__device__ __forceinline__ void layer16_g(const float* __restrict__ w,
                                          const float* __restrict__ b,
                                          const float h[16], float out[16]) {
    float acc[16];
#pragma unroll
    for (int j4 = 0; j4 < 4; ++j4) {
        float4 b4 = *reinterpret_cast<const float4*>(&b[j4 * 4]);
        acc[j4 * 4 + 0] = b4.x;
        acc[j4 * 4 + 1] = b4.y;
        acc[j4 * 4 + 2] = b4.z;
        acc[j4 * 4 + 3] = b4.w;
    }
#pragma unroll
    for (int k = 0; k < 16; ++k) {
        float hk = h[k];
#pragma unroll
        for (int j4 = 0; j4 < 4; ++j4) {
            float4 w4 = *reinterpret_cast<const float4*>(&w[k * 16 + j4 * 4]);
            acc[j4 * 4 + 0] = fmaf(hk, w4.x, acc[j4 * 4 + 0]);
            acc[j4 * 4 + 1] = fmaf(hk, w4.y, acc[j4 * 4 + 1]);
            acc[j4 * 4 + 2] = fmaf(hk, w4.z, acc[j4 * 4 + 2]);
            acc[j4 * 4 + 3] = fmaf(hk, w4.w, acc[j4 * 4 + 3]);
        }
    }
#pragma unroll
    for (int j = 0; j < 16; ++j) out[j] = fast_tanh(acc[j]);
}

__global__ __launch_bounds__(256) void hydro_kernel(
    const float* __restrict__ g_t,
    const float* __restrict__ g_S,
    const float* __restrict__ g_precp,
    const float* __restrict__ g_temp,
    const float* __restrict__ g_lday,
    const float* __restrict__ g_ew1, const float* __restrict__ g_eb1,
    const float* __restrict__ g_ew2, const float* __restrict__ g_eb2,
    const float* __restrict__ g_ew3, const float* __restrict__ g_eb3,
    const float* __restrict__ g_qw1, const float* __restrict__ g_qb1,
    const float* __restrict__ g_qw2, const float* __restrict__ g_qb2,
    const float* __restrict__ g_qw3, const float* __restrict__ g_qb3,
    const float* __restrict__ g_Df, const float* __restrict__ g_Tmax,
    const float* __restrict__ g_Tmin,
    float* __restrict__ g_out, int B)
{
    // packed interp table: {precp, temp, lday, pad} -> 2 ds_read_b128/thread
    __shared__ __align__(16) float4 s_tbl[TLEN];

    const int tx = threadIdx.x;
    for (int i = tx; i < TLEN; i += 256) {
        s_tbl[i] = make_float4(g_precp[i], g_temp[i], g_lday[i], 0.0f);
    }
    __syncthreads();

    const int i = blockIdx.x * 256 + tx;
    if (i >= B) return;

    const float Df   = fminf(fmaxf(g_Df[0],   0.01f), 5.0f);
    const float Tmax = fminf(fmaxf(g_Tmax[0], 0.0f),  3.0f);
    const float Tmin = fminf(fmaxf(g_Tmin[0], -3.0f), 0.0f);
    const float eb3  = g_eb3[0];
    const float qb3  = g_qb3[0];

    const float tv = g_t[i];
    const float2 Sv = reinterpret_cast<const float2*>(g_S)[i];
    const float S_snow = Sv.x, S_water = Sv.y;

    int idx = (int)tv;
    idx = max(0, min(idx, TLEN - 2));
    const float fr = tv - (float)idx;
    const float4 t0 = s_tbl[idx];
    const float4 t1 = s_tbl[idx + 1];
    const float precp = fmaf(fr, t1.x - t0.x, t0.x);
    const float temp  = fmaf(fr, t1.y - t0.y, t0.y);
    const float lday  = fmaf(fr, t1.z - t0.z, t0.z);

    // ===== ET MLP: inputs [S_snow, S_water, temp] =====
    float h1[16];
    {
        float acc[16];
#pragma unroll
        for (int j4 = 0; j4 < 4; ++j4) {
            float4 b4 = *reinterpret_cast<const float4*>(&g_eb1[j4 * 4]);
            float4 w0 = *reinterpret_cast<const float4*>(&g_ew1[0 * 16 + j4 * 4]);
            float4 w1 = *reinterpret_cast<const float4*>(&g_ew1[1 * 16 + j4 * 4]);
            float4 w2 = *reinterpret_cast<const float4*>(&g_ew1[2 * 16 + j4 * 4]);
            acc[j4 * 4 + 0] = fmaf(temp, w2.x, fmaf(S_water, w1.x, fmaf(S_snow, w0.x, b4.x)));
            acc[j4 * 4 + 1] = fmaf(temp, w2.y, fmaf(S_water, w1.y, fmaf(S_snow, w0.y, b4.y)));
            acc[j4 * 4 + 2] = fmaf(temp, w2.z, fmaf(S_water, w1.z, fmaf(S_snow, w0.z, b4.z)));
            acc[j4 * 4 + 3] = fmaf(temp, w2.w, fmaf(S_water, w1.w, fmaf(S_snow, w0.w, b4.w)));
        }
#pragma unroll
        for (int j = 0; j < 16; ++j) h1[j] = fast_tanh(acc[j]);
    }
    float h2[16];
    layer16_g(g_ew2, g_eb2, h1, h2);
    float ET = eb3;
#pragma unroll
    for (int k = 0; k < 16; ++k) ET = fmaf(h2[k], g_ew3[k], ET);

    // ===== Q MLP: inputs [S_water, precp] =====
    float g1[16];
    {
        float acc[16];
#pragma unroll
        for (int j4 = 0; j4 < 4; ++j4) {
            float4 b4 = *reinterpret_cast<const float4*>(&g_qb1[j4 * 4]);
            float4 w0 = *reinterpret_cast<const float4*>(&g_qw1[0 * 16 + j4 * 4]);
            float4 w1 = *reinterpret_cast<const float4*>(&g_qw1[1 * 16 + j4 * 4]);
            acc[j4 * 4 + 0] = fmaf(precp, w1.x, fmaf(S_water, w0.x, b4.x));
            acc[j4 * 4 + 1] = fmaf(precp, w1.y, fmaf(S_water, w0.y, b4.y));
            acc[j4 * 4 + 2] = fmaf(precp, w1.z, fmaf(S_water, w0.z, b4.z));
            acc[j4 * 4 + 3] = fmaf(precp, w1.w, fmaf(S_water, w0.w, b4.w));
        }
#pragma unroll
        for (int j = 0; j < 16; ++j) g1[j] = fast_tanh(acc[j]);
    }
    float g2[16];
    layer16_g(g_qw2, g_qb2, g1, g2);
    float Q = qb3;
#pragma unroll
    for (int k = 0; k < 16; ++k) Q = fmaf(g2[k], g_qw3[k], Q);

    // ===== bucket dynamics =====
    const float sw_step = step_fn(S_water);
    const float melt = step_fn(temp - Tmax) * step_fn(S_snow)
                     * fminf(S_snow, Df * (temp - Tmax));
    const float dS1 = step_fn(Tmin - temp) * precp - melt;
    const float dS2 = step_fn(temp - Tmin) * precp + melt
                    - sw_step * lday * __expf(ET)
                    - sw_step * __expf(Q);

    reinterpret_cast<float2*>(g_out)[i] = make_float2(dS1, dS2);
}

extern "C" void kernel_launch(void* const* d_in, const int* in_sizes, int n_in,
                              void* d_out, int out_size, void* d_ws, size_t ws_size,
                              hipStream_t stream)
{
    const int B = in_sizes[0];
    const int block = 256;
    const int grid = (B + block - 1) / block;
    hipLaunchKernelGGL(hydro_kernel, dim3(grid), dim3(block), 0, stream,
        (const float*)d_in[0],  // t
        (const float*)d_in[1],  // S
        (const float*)d_in[3],  // precp_series
        (const float*)d_in[4],  // temp_series
        (const float*)d_in[5],  // lday_series
        (const float*)d_in[6],  (const float*)d_in[7],
        (const float*)d_in[8],  (const float*)d_in[9],
        (const float*)d_in[10], (const float*)d_in[11],
        (const float*)d_in[12], (const float*)d_in[13],
        (const float*)d_in[14], (const float*)d_in[15],
        (const float*)d_in[16], (const float*)d_in[17],
        (const float*)d_in[21], // Df
        (const float*)d_in[22], // Tmax
        (const float*)d_in[23], // Tmin
        (float*)d_out, B);
}

// Round 3
// 31.817 us; speedup vs baseline: 1.2482x; 1.2482x over previous
//
#include <hip/hip_runtime.h>

#define TLEN 1461

typedef __bf16 bf16x8 __attribute__((ext_vector_type(8)));
typedef float f32x16 __attribute__((ext_vector_type(16)));

union FragU { unsigned u[4]; bf16x8 f; };

__device__ __forceinline__ float fast_tanh(float x) {
    // tanh(x) = 1 - 2/(exp(2x)+1)
    float e = __expf(2.0f * x);
    return fmaf(-2.0f, __builtin_amdgcn_rcpf(e + 1.0f), 1.0f);
}
__device__ __forceinline__ float step_fn(float x) {
    // (tanh(5x)+1)*0.5 == sigmoid(10x)
    float e = __expf(-10.0f * x);
    return __builtin_amdgcn_rcpf(1.0f + e);
}
__device__ __forceinline__ unsigned cvt_pk_bf16(float lo, float hi) {
    unsigned r;
    asm("v_cvt_pk_bf16_f32 %0, %1, %2" : "=v"(r) : "v"(lo), "v"(hi));
    return r;
}
// in-place two-register 32-lane-boundary swap:
// a' = [a(0:31) | b(0:31)], b' = [a(32:63) | b(32:63)]
__device__ __forceinline__ void plswap(unsigned &a, unsigned &b) {
    asm("v_permlane32_swap_b32 %0, %1" : "+v"(a), "+v"(b));
}
__device__ __forceinline__ float plswap_f(float a, float b) {
    unsigned ua = __float_as_uint(a), ub = __float_as_uint(b);
    plswap(ua, ub);
    return __uint_as_float(ua);
}

// h1[16] (fp32, sample-major, |h|<=1) -> layer2 (16x16 tanh) -> layer3 dot -> scalar
// a2 = W2^T A-fragment, jb[8] = b2 in C-row order, a3 = w3 A-fragment (row 0), b3 = bias
__device__ __forceinline__ float mlp_tail(const float h1[16], const FragU a2,
                                          const float jb[8], const FragU a3,
                                          float b3) {
    // pack h1 -> B2 fragments for both 32-sample blocks (k = 8*(lane>>5)+e)
    unsigned lo0 = cvt_pk_bf16(h1[0], h1[1]),  lo1 = cvt_pk_bf16(h1[2], h1[3]);
    unsigned lo2 = cvt_pk_bf16(h1[4], h1[5]),  lo3 = cvt_pk_bf16(h1[6], h1[7]);
    unsigned hi0 = cvt_pk_bf16(h1[8], h1[9]),  hi1 = cvt_pk_bf16(h1[10], h1[11]);
    unsigned hi2 = cvt_pk_bf16(h1[12], h1[13]), hi3 = cvt_pk_bf16(h1[14], h1[15]);
    plswap(lo0, hi0); plswap(lo1, hi1); plswap(lo2, hi2); plswap(lo3, hi3);
    FragU b2a, b2b;
    b2a.u[0] = lo0; b2a.u[1] = lo1; b2a.u[2] = lo2; b2a.u[3] = lo3;
    b2b.u[0] = hi0; b2b.u[1] = hi1; b2b.u[2] = hi2; b2b.u[3] = hi3;

    f32x16 c0, c1;
#pragma unroll
    for (int r = 0; r < 16; ++r) {
        float bv = (r < 8) ? jb[r] : 0.0f;
        c0[r] = bv; c1[r] = bv;
    }
    c0 = __builtin_amdgcn_mfma_f32_32x32x16_bf16(a2.f, b2a.f, c0, 0, 0, 0);
    c1 = __builtin_amdgcn_mfma_f32_32x32x16_bf16(a2.f, b2b.f, c1, 0, 0, 0);

    // tanh in C-layout (regs 0..7 valid: rows j<16), repack -> B3 fragments
    FragU b3a, b3b;
    {
        float t0 = fast_tanh(c0[0]), t1 = fast_tanh(c0[1]);
        float t2 = fast_tanh(c0[2]), t3 = fast_tanh(c0[3]);
        float t4 = fast_tanh(c0[4]), t5 = fast_tanh(c0[5]);
        float t6 = fast_tanh(c0[6]), t7 = fast_tanh(c0[7]);
        unsigned u = cvt_pk_bf16(t0, t1), v = cvt_pk_bf16(t2, t3);
        unsigned w = cvt_pk_bf16(t4, t5), z = cvt_pk_bf16(t6, t7);
        plswap(u, w); plswap(v, z);
        b3a.u[0] = u; b3a.u[1] = v; b3a.u[2] = w; b3a.u[3] = z;
    }
    {
        float t0 = fast_tanh(c1[0]), t1 = fast_tanh(c1[1]);
        float t2 = fast_tanh(c1[2]), t3 = fast_tanh(c1[3]);
        float t4 = fast_tanh(c1[4]), t5 = fast_tanh(c1[5]);
        float t6 = fast_tanh(c1[6]), t7 = fast_tanh(c1[7]);
        unsigned u = cvt_pk_bf16(t0, t1), v = cvt_pk_bf16(t2, t3);
        unsigned w = cvt_pk_bf16(t4, t5), z = cvt_pk_bf16(t6, t7);
        plswap(u, w); plswap(v, z);
        b3b.u[0] = u; b3b.u[1] = v; b3b.u[2] = w; b3b.u[3] = z;
    }

    f32x16 d0, d1;
#pragma unroll
    for (int r = 0; r < 16; ++r) { d0[r] = 0.0f; d1[r] = 0.0f; }
    d0[0] = b3; d1[0] = b3;
    d0 = __builtin_amdgcn_mfma_f32_32x32x16_bf16(a3.f, b3a.f, d0, 0, 0, 0);
    d1 = __builtin_amdgcn_mfma_f32_32x32x16_bf16(a3.f, b3b.f, d1, 0, 0, 0);
    // row0 (reg0, lanes 0-31) of each block -> sample-major across the wave
    return plswap_f(d0[0], d1[0]);
}

__global__ __launch_bounds__(256) void hydro_kernel(
    const float* __restrict__ g_t,
    const float* __restrict__ g_S,
    const float* __restrict__ g_precp,
    const float* __restrict__ g_temp,
    const float* __restrict__ g_lday,
    const float* __restrict__ g_ew1, const float* __restrict__ g_eb1,
    const float* __restrict__ g_ew2, const float* __restrict__ g_eb2,
    const float* __restrict__ g_ew3, const float* __restrict__ g_eb3,
    const float* __restrict__ g_qw1, const float* __restrict__ g_qb1,
    const float* __restrict__ g_qw2, const float* __restrict__ g_qb2,
    const float* __restrict__ g_qw3, const float* __restrict__ g_qb3,
    const float* __restrict__ g_Df, const float* __restrict__ g_Tmax,
    const float* __restrict__ g_Tmin,
    float* __restrict__ g_out, int B)
{
    __shared__ __align__(16) float4 s_tbl[TLEN];

    const int tx = threadIdx.x;
    for (int i = tx; i < TLEN; i += 256) {
        s_tbl[i] = make_float4(g_precp[i], g_temp[i], g_lday[i], 0.0f);
    }
    __syncthreads();

    const int lane = tx & 63;
    const int m  = lane & 31;     // A-fragment row (output feature)
    const int kg = lane >> 5;     // k-group: k = 8*kg + e

    // ---- per-thread weight fragments (loaded once, L1-resident) ----
    FragU a2e, a2q, a3e, a3q;
#pragma unroll
    for (int p = 0; p < 4; ++p) {
        const int k0 = 8 * kg + 2 * p, k1 = k0 + 1;
        const int mm = (m < 16) ? m : 0;
        const float s = (m < 16) ? 1.0f : 0.0f;
        a2e.u[p] = cvt_pk_bf16(s * g_ew2[k0 * 16 + mm], s * g_ew2[k1 * 16 + mm]);
        a2q.u[p] = cvt_pk_bf16(s * g_qw2[k0 * 16 + mm], s * g_qw2[k1 * 16 + mm]);
        const float s3 = (m == 0) ? 1.0f : 0.0f;
        a3e.u[p] = cvt_pk_bf16(s3 * g_ew3[k0], s3 * g_ew3[k1]);
        a3q.u[p] = cvt_pk_bf16(s3 * g_qw3[k0], s3 * g_qw3[k1]);
    }
    float jbe[8], jbq[8];
#pragma unroll
    for (int r = 0; r < 8; ++r) {
        const int j = (r & 3) + 8 * (r >> 2) + 4 * kg;   // C-row for reg r
        jbe[r] = g_eb2[j];
        jbq[r] = g_qb2[j];
    }
    const float eb3 = g_eb3[0];
    const float qb3 = g_qb3[0];

    const float Df   = fminf(fmaxf(g_Df[0],   0.01f), 5.0f);
    const float Tmax = fminf(fmaxf(g_Tmax[0], 0.0f),  3.0f);
    const float Tmin = fminf(fmaxf(g_Tmin[0], -3.0f), 0.0f);

    const int i = blockIdx.x * 256 + tx;
    const int ic = (i < B) ? i : (B - 1);   // clamp: all lanes stay active for cross-lane ops

    const float tv = g_t[ic];
    const float2 Sv = reinterpret_cast<const float2*>(g_S)[ic];
    const float S_snow = Sv.x, S_water = Sv.y;

    int idx = (int)tv;
    idx = max(0, min(idx, TLEN - 2));
    const float fr = tv - (float)idx;
    const float4 t0 = s_tbl[idx];
    const float4 t1 = s_tbl[idx + 1];
    const float precp = fmaf(fr, t1.x - t0.x, t0.x);
    const float temp  = fmaf(fr, t1.y - t0.y, t0.y);
    const float lday  = fmaf(fr, t1.z - t0.z, t0.z);

    // ===== ET MLP layer1 (fp32, sample-major) =====
    float h1e[16];
#pragma unroll
    for (int j4 = 0; j4 < 4; ++j4) {
        float4 b4 = *reinterpret_cast<const float4*>(&g_eb1[j4 * 4]);
        float4 w0 = *reinterpret_cast<const float4*>(&g_ew1[0 * 16 + j4 * 4]);
        float4 w1 = *reinterpret_cast<const float4*>(&g_ew1[1 * 16 + j4 * 4]);
        float4 w2 = *reinterpret_cast<const float4*>(&g_ew1[2 * 16 + j4 * 4]);
        h1e[j4 * 4 + 0] = fast_tanh(fmaf(temp, w2.x, fmaf(S_water, w1.x, fmaf(S_snow, w0.x, b4.x))));
        h1e[j4 * 4 + 1] = fast_tanh(fmaf(temp, w2.y, fmaf(S_water, w1.y, fmaf(S_snow, w0.y, b4.y))));
        h1e[j4 * 4 + 2] = fast_tanh(fmaf(temp, w2.z, fmaf(S_water, w1.z, fmaf(S_snow, w0.z, b4.z))));
        h1e[j4 * 4 + 3] = fast_tanh(fmaf(temp, w2.w, fmaf(S_water, w1.w, fmaf(S_snow, w0.w, b4.w))));
    }
    const float ET = mlp_tail(h1e, a2e, jbe, a3e, eb3);

    // ===== Q MLP layer1 =====
    float h1q[16];
#pragma unroll
    for (int j4 = 0; j4 < 4; ++j4) {
        float4 b4 = *reinterpret_cast<const float4*>(&g_qb1[j4 * 4]);
        float4 w0 = *reinterpret_cast<const float4*>(&g_qw1[0 * 16 + j4 * 4]);
        float4 w1 = *reinterpret_cast<const float4*>(&g_qw1[1 * 16 + j4 * 4]);
        h1q[j4 * 4 + 0] = fast_tanh(fmaf(precp, w1.x, fmaf(S_water, w0.x, b4.x)));
        h1q[j4 * 4 + 1] = fast_tanh(fmaf(precp, w1.y, fmaf(S_water, w0.y, b4.y)));
        h1q[j4 * 4 + 2] = fast_tanh(fmaf(precp, w1.z, fmaf(S_water, w0.z, b4.z)));
        h1q[j4 * 4 + 3] = fast_tanh(fmaf(precp, w1.w, fmaf(S_water, w0.w, b4.w)));
    }
    const float Q = mlp_tail(h1q, a2q, jbq, a3q, qb3);

    // ===== bucket dynamics =====
    const float sw_step = step_fn(S_water);
    const float melt = step_fn(temp - Tmax) * step_fn(S_snow)
                     * fminf(S_snow, Df * (temp - Tmax));
    const float dS1 = step_fn(Tmin - temp) * precp - melt;
    const float dS2 = step_fn(temp - Tmin) * precp + melt
                    - sw_step * lday * __expf(ET)
                    - sw_step * __expf(Q);

    if (i < B) {
        reinterpret_cast<float2*>(g_out)[i] = make_float2(dS1, dS2);
    }
}

extern "C" void kernel_launch(void* const* d_in, const int* in_sizes, int n_in,
                              void* d_out, int out_size, void* d_ws, size_t ws_size,
                              hipStream_t stream)
{
    const int B = in_sizes[0];
    const int block = 256;
    const int grid = (B + block - 1) / block;
    hipLaunchKernelGGL(hydro_kernel, dim3(grid), dim3(block), 0, stream,
        (const float*)d_in[0],  // t
        (const float*)d_in[1],  // S
        (const float*)d_in[3],  // precp_series
        (const float*)d_in[4],  // temp_series
        (const float*)d_in[5],  // lday_series
        (const float*)d_in[6],  (const float*)d_in[7],
        (const float*)d_in[8],  (const float*)d_in[9],
        (const float*)d_in[10], (const float*)d_in[11],
        (const float*)d_in[12], (const float*)d_in[13],
        (const float*)d_in[14], (const float*)d_in[15],
        (const float*)d_in[16], (const float*)d_in[17],
        (const float*)d_in[21], // Df
        (const float*)d_in[22], // Tmax
        (const float*)d_in[23], // Tmin
        (float*)d_out, B);
}

// Round 4
// 28.784 us; speedup vs baseline: 1.3797x; 1.1054x over previous
//
#include <hip/hip_runtime.h>

#define TLEN 1461
#define L2E      1.44269504088896340736f
#define TWO_L2E  2.88539008177792681472f

typedef __bf16 bf16x8 __attribute__((ext_vector_type(8)));
typedef float f32x16 __attribute__((ext_vector_type(16)));

union FragU { unsigned u[4]; bf16x8 f; };

// tanh(x) given y = 2*log2e*x  (scale pre-folded):  1 - 2/(exp2(y)+1)
__device__ __forceinline__ float tanh_pre(float y) {
    float e = __builtin_amdgcn_exp2f(y);
    return fmaf(-2.0f, __builtin_amdgcn_rcpf(e + 1.0f), 1.0f);
}
// (tanh(5x)+1)/2 = sigmoid(10x) = 1/(1+exp2(-10*log2e*x))
__device__ __forceinline__ float step_fn(float x) {
    float e = __builtin_amdgcn_exp2f(x * -14.4269504088896341f);
    return __builtin_amdgcn_rcpf(1.0f + e);
}
__device__ __forceinline__ unsigned cvt_pk_bf16(float lo, float hi) {
    unsigned r;
    asm("v_cvt_pk_bf16_f32 %0, %1, %2" : "=v"(r) : "v"(lo), "v"(hi));
    return r;
}
__device__ __forceinline__ void plswap(unsigned &a, unsigned &b) {
    asm("v_permlane32_swap_b32 %0, %1" : "+v"(a), "+v"(b));
}
__device__ __forceinline__ float plswap_add(float a, float b) {
    unsigned ua = __float_as_uint(a), ub = __float_as_uint(b);
    plswap(ua, ub);
    return __uint_as_float(ua) + __uint_as_float(ub);
}

// pack sample-major h[16] (fp32) into the two 32x32x16 B fragments
__device__ __forceinline__ void pack_b(const float h[16], FragU &ba, FragU &bb) {
    unsigned lo0 = cvt_pk_bf16(h[0], h[1]),   lo1 = cvt_pk_bf16(h[2], h[3]);
    unsigned lo2 = cvt_pk_bf16(h[4], h[5]),   lo3 = cvt_pk_bf16(h[6], h[7]);
    unsigned hi0 = cvt_pk_bf16(h[8], h[9]),   hi1 = cvt_pk_bf16(h[10], h[11]);
    unsigned hi2 = cvt_pk_bf16(h[12], h[13]), hi3 = cvt_pk_bf16(h[14], h[15]);
    plswap(lo0, hi0); plswap(lo1, hi1); plswap(lo2, hi2); plswap(lo3, hi3);
    ba.u[0] = lo0; ba.u[1] = lo1; ba.u[2] = lo2; ba.u[3] = lo3;
    bb.u[0] = hi0; bb.u[1] = hi1; bb.u[2] = hi2; bb.u[3] = hi3;
}

// layer2 (MFMA, pre-scaled weights) + tanh + fp32 dot with w3 -> per-lane scalar
// returns (w3.h2 + b3)*log2e for THIS lane's sample
__device__ __forceinline__ float tail(const FragU a2, const float jb[8],
                                      const float w3v[8], float b3half,
                                      const FragU ba, const FragU bb) {
    f32x16 c0, c1;
#pragma unroll
    for (int r = 0; r < 8; ++r) { c0[r] = jb[r]; c1[r] = jb[r]; }
    c0 = __builtin_amdgcn_mfma_f32_32x32x16_bf16(a2.f, ba.f, c0, 0, 0, 0);
    c1 = __builtin_amdgcn_mfma_f32_32x32x16_bf16(a2.f, bb.f, c1, 0, 0, 0);

    float p0 = b3half, p1 = b3half;
#pragma unroll
    for (int r = 0; r < 8; ++r) {
        p0 = fmaf(tanh_pre(c0[r]), w3v[r], p0);
        p1 = fmaf(tanh_pre(c1[r]), w3v[r], p1);
    }
    return plswap_add(p0, p1);   // lanes 0-31: block0 dot, lanes 32-63: block1 dot
}

__global__ __launch_bounds__(256) void hydro_kernel(
    const float* __restrict__ g_t,
    const float* __restrict__ g_S,
    const float* __restrict__ g_precp,
    const float* __restrict__ g_temp,
    const float* __restrict__ g_lday,
    const float* __restrict__ g_ew1, const float* __restrict__ g_eb1,
    const float* __restrict__ g_ew2, const float* __restrict__ g_eb2,
    const float* __restrict__ g_ew3, const float* __restrict__ g_eb3,
    const float* __restrict__ g_qw1, const float* __restrict__ g_qb1,
    const float* __restrict__ g_qw2, const float* __restrict__ g_qb2,
    const float* __restrict__ g_qw3, const float* __restrict__ g_qb3,
    const float* __restrict__ g_Df, const float* __restrict__ g_Tmax,
    const float* __restrict__ g_Tmin,
    float* __restrict__ g_out, int B)
{
    __shared__ __align__(16) float4 s_tbl[TLEN];

    const int tx = threadIdx.x;
    for (int i = tx; i < TLEN; i += 256) {
        s_tbl[i] = make_float4(g_precp[i], g_temp[i], g_lday[i], 0.0f);
    }
    __syncthreads();

    const int lane = tx & 63;
    const int m  = lane & 31;     // A-fragment row (output feature)
    const int kg = lane >> 5;     // k-group: k = 8*kg + e

    // ---- per-lane weight fragments (one-time, pre-scaled by 2*log2e) ----
    FragU a2e, a2q;
#pragma unroll
    for (int p = 0; p < 4; ++p) {
        const int k0 = 8 * kg + 2 * p, k1 = k0 + 1;
        const int mm = (m < 16) ? m : 0;
        const float s = (m < 16) ? TWO_L2E : 0.0f;
        a2e.u[p] = cvt_pk_bf16(s * g_ew2[k0 * 16 + mm], s * g_ew2[k1 * 16 + mm]);
        a2q.u[p] = cvt_pk_bf16(s * g_qw2[k0 * 16 + mm], s * g_qw2[k1 * 16 + mm]);
    }
    float jbe[8], jbq[8], w3ve[8], w3vq[8];
#pragma unroll
    for (int r = 0; r < 8; ++r) {
        const int j = (r & 3) + 8 * (r >> 2) + 4 * kg;   // C-row for reg r
        jbe[r]  = TWO_L2E * g_eb2[j];
        jbq[r]  = TWO_L2E * g_qb2[j];
        w3ve[r] = L2E * g_ew3[j];
        w3vq[r] = L2E * g_qw3[j];
    }
    const float b3e_half = (kg == 0) ? L2E * g_eb3[0] : 0.0f;
    const float b3q_half = (kg == 0) ? L2E * g_qb3[0] : 0.0f;

    const float Df   = fminf(fmaxf(g_Df[0],   0.01f), 5.0f);
    const float Tmax = fminf(fmaxf(g_Tmax[0], 0.0f),  3.0f);
    const float Tmin = fminf(fmaxf(g_Tmin[0], -3.0f), 0.0f);

    const int i = blockIdx.x * 256 + tx;
    const int ic = (i < B) ? i : (B - 1);   // clamp: all lanes active for cross-lane ops

    const float tv = g_t[ic];
    const float2 Sv = reinterpret_cast<const float2*>(g_S)[ic];
    const float S_snow = Sv.x, S_water = Sv.y;

    int idx = (int)tv;
    idx = max(0, min(idx, TLEN - 2));
    const float fr = tv - (float)idx;
    const float4 t0 = s_tbl[idx];
    const float4 t1 = s_tbl[idx + 1];
    const float precp = fmaf(fr, t1.x - t0.x, t0.x);
    const float temp  = fmaf(fr, t1.y - t0.y, t0.y);
    const float lday  = fmaf(fr, t1.z - t0.z, t0.z);

    // ===== layer1 (fp32, sample-major), tanh input scaled by 2*log2e =====
    float h1e[16], h1q[16];
#pragma unroll
    for (int j4 = 0; j4 < 4; ++j4) {
        float4 b4 = *reinterpret_cast<const float4*>(&g_eb1[j4 * 4]);
        float4 w0 = *reinterpret_cast<const float4*>(&g_ew1[0 * 16 + j4 * 4]);
        float4 w1 = *reinterpret_cast<const float4*>(&g_ew1[1 * 16 + j4 * 4]);
        float4 w2 = *reinterpret_cast<const float4*>(&g_ew1[2 * 16 + j4 * 4]);
        h1e[j4 * 4 + 0] = tanh_pre(TWO_L2E * fmaf(temp, w2.x, fmaf(S_water, w1.x, fmaf(S_snow, w0.x, b4.x))));
        h1e[j4 * 4 + 1] = tanh_pre(TWO_L2E * fmaf(temp, w2.y, fmaf(S_water, w1.y, fmaf(S_snow, w0.y, b4.y))));
        h1e[j4 * 4 + 2] = tanh_pre(TWO_L2E * fmaf(temp, w2.z, fmaf(S_water, w1.z, fmaf(S_snow, w0.z, b4.z))));
        h1e[j4 * 4 + 3] = tanh_pre(TWO_L2E * fmaf(temp, w2.w, fmaf(S_water, w1.w, fmaf(S_snow, w0.w, b4.w))));
    }
#pragma unroll
    for (int j4 = 0; j4 < 4; ++j4) {
        float4 b4 = *reinterpret_cast<const float4*>(&g_qb1[j4 * 4]);
        float4 w0 = *reinterpret_cast<const float4*>(&g_qw1[0 * 16 + j4 * 4]);
        float4 w1 = *reinterpret_cast<const float4*>(&g_qw1[1 * 16 + j4 * 4]);
        h1q[j4 * 4 + 0] = tanh_pre(TWO_L2E * fmaf(precp, w1.x, fmaf(S_water, w0.x, b4.x)));
        h1q[j4 * 4 + 1] = tanh_pre(TWO_L2E * fmaf(precp, w1.y, fmaf(S_water, w0.y, b4.y)));
        h1q[j4 * 4 + 2] = tanh_pre(TWO_L2E * fmaf(precp, w1.z, fmaf(S_water, w0.z, b4.z)));
        h1q[j4 * 4 + 3] = tanh_pre(TWO_L2E * fmaf(precp, w1.w, fmaf(S_water, w0.w, b4.w)));
    }

    FragU bae, bbe, baq, bbq;
    pack_b(h1e, bae, bbe);
    pack_b(h1q, baq, bbq);

    // ===== layer2 MFMA + tanh + fp32 layer3 dot (ET/Q come back *log2e) =====
    const float ETs = tail(a2e, jbe, w3ve, b3e_half, bae, bbe);
    const float Qs  = tail(a2q, jbq, w3vq, b3q_half, baq, bbq);

    // ===== bucket dynamics (exp(ET) = exp2(ETs), scale pre-folded) =====
    const float sw_step = step_fn(S_water);
    const float melt = step_fn(temp - Tmax) * step_fn(S_snow)
                     * fminf(S_snow, Df * (temp - Tmax));
    const float dS1 = step_fn(Tmin - temp) * precp - melt;
    const float dS2 = step_fn(temp - Tmin) * precp + melt
                    - sw_step * lday * __builtin_amdgcn_exp2f(ETs)
                    - sw_step * __builtin_amdgcn_exp2f(Qs);

    if (i < B) {
        reinterpret_cast<float2*>(g_out)[i] = make_float2(dS1, dS2);
    }
}

extern "C" void kernel_launch(void* const* d_in, const int* in_sizes, int n_in,
                              void* d_out, int out_size, void* d_ws, size_t ws_size,
                              hipStream_t stream)
{
    const int B = in_sizes[0];
    const int block = 256;
    const int grid = (B + block - 1) / block;
    hipLaunchKernelGGL(hydro_kernel, dim3(grid), dim3(block), 0, stream,
        (const float*)d_in[0],  // t
        (const float*)d_in[1],  // S
        (const float*)d_in[3],  // precp_series
        (const float*)d_in[4],  // temp_series
        (const float*)d_in[5],  // lday_series
        (const float*)d_in[6],  (const float*)d_in[7],
        (const float*)d_in[8],  (const float*)d_in[9],
        (const float*)d_in[10], (const float*)d_in[11],
        (const float*)d_in[12], (const float*)d_in[13],
        (const float*)d_in[14], (const float*)d_in[15],
        (const float*)d_in[16], (const float*)d_in[17],
        (const float*)d_in[21], // Df
        (const float*)d_in[22], // Tmax
        (const float*)d_in[23], // Tmin
        (float*)d_out, B);
}

// Round 5
// 26.687 us; speedup vs baseline: 1.4881x; 1.0786x over previous
//
#include <hip/hip_runtime.h>

#define TLEN 1461
#define L2E      1.44269504088896340736f
#define TWO_L2E  2.88539008177792681472f

typedef __bf16 bf16x8 __attribute__((ext_vector_type(8)));
typedef float f32x16 __attribute__((ext_vector_type(16)));

union FragU { unsigned u[4]; bf16x8 f; };

__device__ __forceinline__ float step_fn(float x) {
    // (tanh(5x)+1)/2 = sigmoid(10x) = 1/(1+exp2(-10*log2e*x))
    float e = __builtin_amdgcn_exp2f(x * -14.4269504088896341f);
    return __builtin_amdgcn_rcpf(1.0f + e);
}
__device__ __forceinline__ unsigned cvt_pk_bf16(float lo, float hi) {
    unsigned r;
    asm("v_cvt_pk_bf16_f32 %0, %1, %2" : "=v"(r) : "v"(lo), "v"(hi));
    return r;
}
__device__ __forceinline__ void plswap(unsigned &a, unsigned &b) {
    asm("v_permlane32_swap_b32 %0, %1" : "+v"(a), "+v"(b));
}
__device__ __forceinline__ float plswap_add(float a, float b) {
    unsigned ua = __float_as_uint(a), ub = __float_as_uint(b);
    plswap(ua, ub);
    return __uint_as_float(ua) + __uint_as_float(ub);
}

// layer1 quad: 4 pre-activations (already *2*log2e) -> tanh -> 2 packed bf16 words
__device__ __forceinline__ void quad_tanh_pack(float y0, float y1, float y2, float y3,
                                               unsigned &wlo, unsigned &whi) {
    float s0 = __builtin_amdgcn_rcpf(1.0f + __builtin_amdgcn_exp2f(y0));
    float s1 = __builtin_amdgcn_rcpf(1.0f + __builtin_amdgcn_exp2f(y1));
    float s2 = __builtin_amdgcn_rcpf(1.0f + __builtin_amdgcn_exp2f(y2));
    float s3 = __builtin_amdgcn_rcpf(1.0f + __builtin_amdgcn_exp2f(y3));
    float h0 = fmaf(-2.0f, s0, 1.0f), h1 = fmaf(-2.0f, s1, 1.0f);
    float h2 = fmaf(-2.0f, s2, 1.0f), h3 = fmaf(-2.0f, s3, 1.0f);
    wlo = cvt_pk_bf16(h0, h1);
    whi = cvt_pk_bf16(h2, h3);
}

// layer2 MFMA + sigma-folded fp32 dot. Returns l2e*(w3.tanh(a2)+b3) for this lane's sample.
// pinit = l2e*(0.5*b3 + sum8(w3_raw over this lane's rows)); w3n[r] = -2*l2e*w3_raw
__device__ __forceinline__ float tail(const FragU a2, const float jb[8],
                                      const float w3n[8], float pinit,
                                      const FragU ba, const FragU bb) {
    f32x16 c0, c1;
#pragma unroll
    for (int r = 0; r < 8; ++r) { c0[r] = jb[r]; c1[r] = jb[r]; }
    c0 = __builtin_amdgcn_mfma_f32_32x32x16_bf16(a2.f, ba.f, c0, 0, 0, 0);
    c1 = __builtin_amdgcn_mfma_f32_32x32x16_bf16(a2.f, bb.f, c1, 0, 0, 0);

    float p0 = pinit, p1 = pinit;
#pragma unroll
    for (int r = 0; r < 8; ++r) {
        float s0 = __builtin_amdgcn_rcpf(1.0f + __builtin_amdgcn_exp2f(c0[r]));
        float s1 = __builtin_amdgcn_rcpf(1.0f + __builtin_amdgcn_exp2f(c1[r]));
        p0 = fmaf(w3n[r], s0, p0);
        p1 = fmaf(w3n[r], s1, p1);
    }
    return plswap_add(p0, p1);
}

struct Weights {
    FragU a2e, a2q;
    float jbe[8], jbq[8], w3ne[8], w3nq[8];
    float pinit_e, pinit_q;
    float Df, Tmax, Tmin;
};

// full per-sample pipeline (layer1 fp32 VALU, layer2 MFMA, dynamics)
__device__ __forceinline__ float2 sample_pipeline(
    float tv, float S_snow, float S_water,
    const float4* __restrict__ s_tbl, const Weights &W,
    const float* __restrict__ g_ew1, const float* __restrict__ g_eb1,
    const float* __restrict__ g_qw1, const float* __restrict__ g_qb1)
{
    int idx = (int)tv;
    idx = max(0, min(idx, TLEN - 2));
    const float fr = tv - (float)idx;
    const float4 t0 = s_tbl[idx];
    const float4 t1 = s_tbl[idx + 1];
    const float precp = fmaf(fr, t1.x - t0.x, t0.x);
    const float temp  = fmaf(fr, t1.y - t0.y, t0.y);
    const float lday  = fmaf(fr, t1.z - t0.z, t0.z);

    // ===== layer1 (fp32, sample-major), fused quad->pack =====
    unsigned elo[4], ehi[4], qlo[4], qhi[4];
#pragma unroll
    for (int j4 = 0; j4 < 4; ++j4) {
        float4 b4 = *reinterpret_cast<const float4*>(&g_eb1[j4 * 4]);
        float4 w0 = *reinterpret_cast<const float4*>(&g_ew1[0 * 16 + j4 * 4]);
        float4 w1 = *reinterpret_cast<const float4*>(&g_ew1[1 * 16 + j4 * 4]);
        float4 w2 = *reinterpret_cast<const float4*>(&g_ew1[2 * 16 + j4 * 4]);
        float y0 = TWO_L2E * fmaf(temp, w2.x, fmaf(S_water, w1.x, fmaf(S_snow, w0.x, b4.x)));
        float y1 = TWO_L2E * fmaf(temp, w2.y, fmaf(S_water, w1.y, fmaf(S_snow, w0.y, b4.y)));
        float y2 = TWO_L2E * fmaf(temp, w2.z, fmaf(S_water, w1.z, fmaf(S_snow, w0.z, b4.z)));
        float y3 = TWO_L2E * fmaf(temp, w2.w, fmaf(S_water, w1.w, fmaf(S_snow, w0.w, b4.w)));
        unsigned wl, wh;
        quad_tanh_pack(y0, y1, y2, y3, wl, wh);
        if (j4 < 2) { elo[j4 * 2] = wl; elo[j4 * 2 + 1] = wh; }
        else        { ehi[(j4 - 2) * 2] = wl; ehi[(j4 - 2) * 2 + 1] = wh; }
    }
#pragma unroll
    for (int j4 = 0; j4 < 4; ++j4) {
        float4 b4 = *reinterpret_cast<const float4*>(&g_qb1[j4 * 4]);
        float4 w0 = *reinterpret_cast<const float4*>(&g_qw1[0 * 16 + j4 * 4]);
        float4 w1 = *reinterpret_cast<const float4*>(&g_qw1[1 * 16 + j4 * 4]);
        float y0 = TWO_L2E * fmaf(precp, w1.x, fmaf(S_water, w0.x, b4.x));
        float y1 = TWO_L2E * fmaf(precp, w1.y, fmaf(S_water, w0.y, b4.y));
        float y2 = TWO_L2E * fmaf(precp, w1.z, fmaf(S_water, w0.z, b4.z));
        float y3 = TWO_L2E * fmaf(precp, w1.w, fmaf(S_water, w0.w, b4.w));
        unsigned wl, wh;
        quad_tanh_pack(y0, y1, y2, y3, wl, wh);
        if (j4 < 2) { qlo[j4 * 2] = wl; qlo[j4 * 2 + 1] = wh; }
        else        { qhi[(j4 - 2) * 2] = wl; qhi[(j4 - 2) * 2 + 1] = wh; }
    }

    // distribute to the two 32-sample B blocks
    FragU bae, bbe, baq, bbq;
#pragma unroll
    for (int p = 0; p < 4; ++p) {
        unsigned l = elo[p], h = ehi[p];
        plswap(l, h);
        bae.u[p] = l; bbe.u[p] = h;
        l = qlo[p]; h = qhi[p];
        plswap(l, h);
        baq.u[p] = l; bbq.u[p] = h;
    }

    const float ETs = tail(W.a2e, W.jbe, W.w3ne, W.pinit_e, bae, bbe);
    const float Qs  = tail(W.a2q, W.jbq, W.w3nq, W.pinit_q, baq, bbq);

    // ===== bucket dynamics =====
    const float sw_step = step_fn(S_water);
    const float sp      = step_fn(temp - W.Tmin);         // step(temp-Tmin); complement for Tmin-temp
    const float melt = step_fn(temp - W.Tmax) * step_fn(S_snow)
                     * fminf(S_snow, W.Df * (temp - W.Tmax));
    const float dS1 = (1.0f - sp) * precp - melt;
    const float dS2 = sp * precp + melt
                    - sw_step * fmaf(lday, __builtin_amdgcn_exp2f(ETs),
                                     __builtin_amdgcn_exp2f(Qs));
    return make_float2(dS1, dS2);
}

__global__ __launch_bounds__(256) void hydro_kernel(
    const float* __restrict__ g_t,
    const float* __restrict__ g_S,
    const float* __restrict__ g_precp,
    const float* __restrict__ g_temp,
    const float* __restrict__ g_lday,
    const float* __restrict__ g_ew1, const float* __restrict__ g_eb1,
    const float* __restrict__ g_ew2, const float* __restrict__ g_eb2,
    const float* __restrict__ g_ew3, const float* __restrict__ g_eb3,
    const float* __restrict__ g_qw1, const float* __restrict__ g_qb1,
    const float* __restrict__ g_qw2, const float* __restrict__ g_qb2,
    const float* __restrict__ g_qw3, const float* __restrict__ g_qb3,
    const float* __restrict__ g_Df, const float* __restrict__ g_Tmax,
    const float* __restrict__ g_Tmin,
    float* __restrict__ g_out, int B)
{
    __shared__ __align__(16) float4 s_tbl[TLEN];

    const int tx = threadIdx.x;
    for (int i = tx; i < TLEN; i += 256) {
        s_tbl[i] = make_float4(g_precp[i], g_temp[i], g_lday[i], 0.0f);
    }
    __syncthreads();

    const int lane = tx & 63;
    const int m  = lane & 31;     // A-fragment row (output feature)
    const int kg = lane >> 5;     // k-group: k = 8*kg + e

    Weights W;
#pragma unroll
    for (int p = 0; p < 4; ++p) {
        const int k0 = 8 * kg + 2 * p, k1 = k0 + 1;
        const int mm = (m < 16) ? m : 0;
        const float s = (m < 16) ? TWO_L2E : 0.0f;
        W.a2e.u[p] = cvt_pk_bf16(s * g_ew2[k0 * 16 + mm], s * g_ew2[k1 * 16 + mm]);
        W.a2q.u[p] = cvt_pk_bf16(s * g_qw2[k0 * 16 + mm], s * g_qw2[k1 * 16 + mm]);
    }
    float sum_e = 0.0f, sum_q = 0.0f;
#pragma unroll
    for (int r = 0; r < 8; ++r) {
        const int j = (r & 3) + 8 * (r >> 2) + 4 * kg;   // C-row for reg r
        W.jbe[r] = TWO_L2E * g_eb2[j];
        W.jbq[r] = TWO_L2E * g_qb2[j];
        const float w3e = g_ew3[j], w3q = g_qw3[j];
        sum_e += w3e; sum_q += w3q;
        W.w3ne[r] = -2.0f * L2E * w3e;
        W.w3nq[r] = -2.0f * L2E * w3q;
    }
    W.pinit_e = L2E * fmaf(0.5f, g_eb3[0], sum_e);
    W.pinit_q = L2E * fmaf(0.5f, g_qb3[0], sum_q);

    W.Df   = fminf(fmaxf(g_Df[0],   0.01f), 5.0f);
    W.Tmax = fminf(fmaxf(g_Tmax[0], 0.0f),  3.0f);
    W.Tmin = fminf(fmaxf(g_Tmin[0], -3.0f), 0.0f);

    // two samples per thread: i0 = blk*512 + tx, i1 = i0 + 256
    const int i0 = blockIdx.x * 512 + tx;
    const int i1 = i0 + 256;
    const int c0i = (i0 < B) ? i0 : (B - 1);
    const int c1i = (i1 < B) ? i1 : (B - 1);

    const float tv0 = g_t[c0i];
    const float tv1 = g_t[c1i];
    const float2 Sv0 = reinterpret_cast<const float2*>(g_S)[c0i];
    const float2 Sv1 = reinterpret_cast<const float2*>(g_S)[c1i];

    const float2 r0 = sample_pipeline(tv0, Sv0.x, Sv0.y, s_tbl, W,
                                      g_ew1, g_eb1, g_qw1, g_qb1);
    const float2 r1 = sample_pipeline(tv1, Sv1.x, Sv1.y, s_tbl, W,
                                      g_ew1, g_eb1, g_qw1, g_qb1);

    if (i0 < B) reinterpret_cast<float2*>(g_out)[i0] = r0;
    if (i1 < B) reinterpret_cast<float2*>(g_out)[i1] = r1;
}

extern "C" void kernel_launch(void* const* d_in, const int* in_sizes, int n_in,
                              void* d_out, int out_size, void* d_ws, size_t ws_size,
                              hipStream_t stream)
{
    const int B = in_sizes[0];
    const int block = 256;
    const int grid = (B + 511) / 512;
    hipLaunchKernelGGL(hydro_kernel, dim3(grid), dim3(block), 0, stream,
        (const float*)d_in[0],  // t
        (const float*)d_in[1],  // S
        (const float*)d_in[3],  // precp_series
        (const float*)d_in[4],  // temp_series
        (const float*)d_in[5],  // lday_series
        (const float*)d_in[6],  (const float*)d_in[7],
        (const float*)d_in[8],  (const float*)d_in[9],
        (const float*)d_in[10], (const float*)d_in[11],
        (const float*)d_in[12], (const float*)d_in[13],
        (const float*)d_in[14], (const float*)d_in[15],
        (const float*)d_in[16], (const float*)d_in[17],
        (const float*)d_in[21], // Df
        (const float*)d_in[22], // Tmax
        (const float*)d_in[23], // Tmin
        (float*)d_out, B);
}